// Round 7
// baseline (43.986 us; speedup 1.0000x reference)
//
#include <hip/hip_runtime.h>
#include <stdint.h>

// Contrastive loss: B=16384, C=1000, D=128, fp32 in, scalar fp32 out.
// dist = f2 + c2 - 2*cross; loss = sum(relu(1-dist) over j!=target)/B.
//
// Round 7: r3's best-measured structure (prep converts B once -> bpre; closs
// waves read L2-hot bpre fragments) + single-pass finish: the reduce kernel
// is folded into closs via the "last block done" pattern (counter zeroed by
// prep each call -> deterministic under graph replay). 2 nodes total, no
// redundant conversion (r6's mistake), no contended atomics (r2->r3 lesson).
#define B_N 16384
#define C_N 1000
#define D_N 128
#define NB_TOT 64          // 1024 padded columns / 16
#define MARGIN 1.0f
#define NBLK 1024          // closs grid (4 x 256)

typedef __attribute__((ext_vector_type(8))) short short8;  // 8 bf16
typedef __attribute__((ext_vector_type(4))) float f32x4;   // MFMA acc

__device__ __forceinline__ short f2bf(float f) {
    union { float f; uint32_t u; } v; v.f = f;
    uint32_t u = v.u;
    return (short)((u + 0x7FFFu + ((u >> 16) & 1u)) >> 16);
}

__device__ __forceinline__ short8 cvt8(const float4& v0, const float4& v1) {
    short8 s;
    s[0] = f2bf(v0.x); s[1] = f2bf(v0.y); s[2] = f2bf(v0.z); s[3] = f2bf(v0.w);
    s[4] = f2bf(v1.x); s[5] = f2bf(v1.y); s[6] = f2bf(v1.z); s[7] = f2bf(v1.w);
    return s;
}

// ---- kernel 1: cls -> bf16 fragment order + c2 (1e30 sentinel past C_N)
// + zero the completion counter. Fragment (nb,kk): lane (l15,kg) holds
// cls[nb*16+l15][kk*32+kg*8 .. +8] at shorts nb*2048 + kk*512 + lane*8.
__global__ __launch_bounds__(64) void prep_kernel(
    const float* __restrict__ cls, short* __restrict__ bpre,
    float* __restrict__ c2p, unsigned int* __restrict__ cnt)
{
    const int nb   = blockIdx.x;       // 0..63
    const int lane = threadIdx.x;      // 0..63
    const int l15  = lane & 15;
    const int kg   = lane >> 4;
    const int col  = nb * 16 + l15;
    const bool valid = col < C_N;

    float sq = 0.f;
    #pragma unroll
    for (int kk = 0; kk < 4; ++kk) {
        float4 v0 = make_float4(0.f, 0.f, 0.f, 0.f);
        float4 v1 = make_float4(0.f, 0.f, 0.f, 0.f);
        if (valid) {
            const float* p = cls + (size_t)col * D_N + kk * 32 + kg * 8;
            v0 = *reinterpret_cast<const float4*>(p);
            v1 = *reinterpret_cast<const float4*>(p + 4);
        }
        sq += v0.x*v0.x + v0.y*v0.y + v0.z*v0.z + v0.w*v0.w
            + v1.x*v1.x + v1.y*v1.y + v1.z*v1.z + v1.w*v1.w;
        *reinterpret_cast<short8*>(bpre + (size_t)(nb * 2048 + kk * 512 + lane * 8))
            = cvt8(v0, v1);
    }
    sq += __shfl_xor(sq, 16);
    sq += __shfl_xor(sq, 32);
    if (lane < 16)
        c2p[nb * 16 + lane] = ((nb * 16 + lane) < C_N) ? sq : 1e30f;
    if (nb == 0 && lane == 0) cnt[0] = 0u;
}

// ---- kernel 2: fused GEMM + hinge + single-pass global reduce ----
__global__ __launch_bounds__(256, 4) void closs_kernel(
    const float* __restrict__ feat, const long long* __restrict__ tgt,
    const short* __restrict__ bpre, const float* __restrict__ c2p,
    float* __restrict__ part, unsigned int* __restrict__ cnt,
    float* __restrict__ out)
{
    const int tid  = threadIdx.x;
    const int wave = tid >> 6;
    const int lane = tid & 63;
    const int l15  = lane & 15;
    const int kg   = lane >> 4;
    const int row0 = blockIdx.y * 64 + wave * 16;   // wave's 16-row base
    const int nb0  = blockIdx.x * (NB_TOT / 4);     // 16 col-blocks per block

    // A fragments (16 rows x K=128) straight into registers, + f2 on the fly.
    short8 a[4];
    float sq = 0.f;
    const float* ap = feat + (size_t)(row0 + l15) * D_N + kg * 8;
    #pragma unroll
    for (int kk = 0; kk < 4; ++kk) {
        float4 v0 = *reinterpret_cast<const float4*>(ap + kk * 32);
        float4 v1 = *reinterpret_cast<const float4*>(ap + kk * 32 + 4);
        sq += v0.x*v0.x + v0.y*v0.y + v0.z*v0.z + v0.w*v0.w
            + v1.x*v1.x + v1.y*v1.y + v1.z*v1.z + v1.w*v1.w;
        a[kk] = cvt8(v0, v1);
    }
    sq += __shfl_xor(sq, 16);
    sq += __shfl_xor(sq, 32);
    float t[4]; int tg[4];
    #pragma unroll
    for (int r = 0; r < 4; ++r) {
        t[r]  = MARGIN - __shfl(sq, kg * 4 + r);
        tg[r] = (int)tgt[row0 + kg * 4 + r];        // int64 targets
    }

    float hsum = 0.f;
    #pragma unroll 4
    for (int i = 0; i < NB_TOT / 4; ++i) {
        const int nb = nb0 + i;
        const short8* bp =
            reinterpret_cast<const short8*>(bpre + (size_t)nb * 2048) + lane;
        short8 b0 = bp[0];
        short8 b1 = bp[64];
        short8 b2 = bp[128];
        short8 b3 = bp[192];
        f32x4 acc = (f32x4){0.f, 0.f, 0.f, 0.f};
        acc = __builtin_amdgcn_mfma_f32_16x16x32_bf16(a[0], b0, acc, 0, 0, 0);
        acc = __builtin_amdgcn_mfma_f32_16x16x32_bf16(a[1], b1, acc, 0, 0, 0);
        acc = __builtin_amdgcn_mfma_f32_16x16x32_bf16(a[2], b2, acc, 0, 0, 0);
        acc = __builtin_amdgcn_mfma_f32_16x16x32_bf16(a[3], b3, acc, 0, 0, 0);
        // C/D layout (m89): col = lane&15, row = kg*4 + r.
        const int   col = nb * 16 + l15;
        const float c2v = c2p[col];     // 1e30 for padded cols -> h = 0
        #pragma unroll
        for (int r = 0; r < 4; ++r) {
            const float u = __builtin_fmaf(2.0f, acc[r], t[r] - c2v);
            hsum += (col != tg[r]) ? fmaxf(0.0f, u) : 0.0f;
        }
    }

    // ---- block partial -> part[], then last-done block finishes ----
    #pragma unroll
    for (int off = 32; off; off >>= 1) hsum += __shfl_down(hsum, off);
    __shared__ float ws[4];
    __shared__ int lastFlag;
    if (lane == 0) ws[wave] = hsum;
    __syncthreads();
    const int bid = blockIdx.y * gridDim.x + blockIdx.x;
    if (tid == 0) {
        part[bid] = ws[0] + ws[1] + ws[2] + ws[3];
        __threadfence();                             // make partial visible
        const unsigned int old = atomicAdd(cnt, 1u); // device-scope
        lastFlag = (old == NBLK - 1) ? 1 : 0;
    }
    __syncthreads();
    if (lastFlag) {
        __threadfence();
        float s = 0.f;
        #pragma unroll
        for (int i = 0; i < 4; ++i)
            s += __hip_atomic_load(&part[tid + i * 256], __ATOMIC_RELAXED,
                                   __HIP_MEMORY_SCOPE_AGENT);
        #pragma unroll
        for (int off = 32; off; off >>= 1) s += __shfl_down(s, off);
        __shared__ float fs[4];
        if (lane == 0) fs[wave] = s;
        __syncthreads();
        if (tid == 0)
            out[0] = (fs[0] + fs[1] + fs[2] + fs[3]) * (1.0f / 16384.0f);
    }
}

extern "C" void kernel_launch(void* const* d_in, const int* in_sizes, int n_in,
                              void* d_out, int out_size, void* d_ws, size_t ws_size,
                              hipStream_t stream) {
    const float*     feat = (const float*)d_in[0];
    const long long* tgt  = (const long long*)d_in[1];   // int64 targets
    const float*     cls  = (const float*)d_in[2];
    float*           out  = (float*)d_out;

    short* bpre = (short*)d_ws;                                        // 256 KiB
    float* c2p  = (float*)((char*)d_ws + 64 * 2048 * sizeof(short));   // 4 KiB
    float* part = c2p + 1024;                                          // 4 KiB
    unsigned int* cnt = (unsigned int*)(part + NBLK);                  // 4 B

    prep_kernel<<<64, 64, 0, stream>>>(cls, bpre, c2p, cnt);
    closs_kernel<<<dim3(4, 256), 256, 0, stream>>>(feat, tgt, bpre, c2p,
                                                   part, cnt, out);
}

// Round 8
// 29.263 us; speedup vs baseline: 1.5031x; 1.5031x over previous
//
#include <hip/hip_runtime.h>
#include <stdint.h>

// Contrastive loss: B=16384, C=1000, D=128, fp32 in, scalar fp32 out.
// dist = f2 + c2 - 2*cross; loss = sum(relu(1-dist) over j!=target)/B.
//
// Round 8: r3's proven 3-node structure (best: 26.4us), with closs reshaped:
// wave = 32 rows x 128 cols (was 16x256) -> total B-frag L2 traffic halves
// (256->128 MB) at unchanged occupancy (1024 blocks, 4/CU, 4 waves/SIMD),
// and a wave-uniform fast-path epilogue (hinges are ~never active: compute
// max of the 8 hinge args, skip mask+accumulate unless __any(mx>0) --
// correct for any data). Lessons kept: no same-addr atomics (~16ns each,
// serialized: r2/r4/r7), B converted once by prep (r6's redundancy cost).
#define B_N 16384
#define C_N 1000
#define D_N 128
#define MARGIN 1.0f

typedef __attribute__((ext_vector_type(8))) short short8;  // 8 bf16
typedef __attribute__((ext_vector_type(4))) float f32x4;   // MFMA acc

__device__ __forceinline__ short f2bf(float f) {
    union { float f; uint32_t u; } v; v.f = f;
    uint32_t u = v.u;
    return (short)((u + 0x7FFFu + ((u >> 16) & 1u)) >> 16);
}

__device__ __forceinline__ short8 cvt8(const float4& v0, const float4& v1) {
    short8 s;
    s[0] = f2bf(v0.x); s[1] = f2bf(v0.y); s[2] = f2bf(v0.z); s[3] = f2bf(v0.w);
    s[4] = f2bf(v1.x); s[5] = f2bf(v1.y); s[6] = f2bf(v1.z); s[7] = f2bf(v1.w);
    return s;
}

// ---- kernel 1: cls -> bf16 fragment order + c2 (1e30 sentinel past C_N).
// Fragment (nb,kk): lane (l15,kg) holds cls[nb*16+l15][kk*32+kg*8 .. +8]
// at shorts nb*2048 + kk*512 + lane*8.
__global__ __launch_bounds__(64) void prep_kernel(
    const float* __restrict__ cls, short* __restrict__ bpre,
    float* __restrict__ c2p)
{
    const int nb   = blockIdx.x;       // 0..63
    const int lane = threadIdx.x;      // 0..63
    const int l15  = lane & 15;
    const int kg   = lane >> 4;
    const int col  = nb * 16 + l15;
    const bool valid = col < C_N;

    float sq = 0.f;
    #pragma unroll
    for (int kk = 0; kk < 4; ++kk) {
        float4 v0 = make_float4(0.f, 0.f, 0.f, 0.f);
        float4 v1 = make_float4(0.f, 0.f, 0.f, 0.f);
        if (valid) {
            const float* p = cls + (size_t)col * D_N + kk * 32 + kg * 8;
            v0 = *reinterpret_cast<const float4*>(p);
            v1 = *reinterpret_cast<const float4*>(p + 4);
        }
        sq += v0.x*v0.x + v0.y*v0.y + v0.z*v0.z + v0.w*v0.w
            + v1.x*v1.x + v1.y*v1.y + v1.z*v1.z + v1.w*v1.w;
        *reinterpret_cast<short8*>(bpre + (size_t)(nb * 2048 + kk * 512 + lane * 8))
            = cvt8(v0, v1);
    }
    sq += __shfl_xor(sq, 16);
    sq += __shfl_xor(sq, 32);
    if (lane < 16)
        c2p[nb * 16 + lane] = ((nb * 16 + lane) < C_N) ? sq : 1e30f;
}

// ---- kernel 2: block = 128 rows x 128 cols; wave = 32 rows x 128 cols ----
__global__ __launch_bounds__(256, 4) void closs_kernel(
    const float* __restrict__ feat, const long long* __restrict__ tgt,
    const short* __restrict__ bpre, const float* __restrict__ c2p,
    float* __restrict__ part)
{
    const int tid  = threadIdx.x;
    const int wave = tid >> 6;
    const int lane = tid & 63;
    const int l15  = lane & 15;
    const int kg   = lane >> 4;
    const int row0 = blockIdx.y * 128 + wave * 32;  // wave's 32-row base
    const int nb0  = blockIdx.x * 8;                // 8 col-blocks per block

    // c2 for this lane's 8 columns (hoisted; overlaps A loads below).
    float c2v[8];
    #pragma unroll
    for (int i = 0; i < 8; ++i) c2v[i] = c2p[(nb0 + i) * 16 + l15];

    // ---- A prologue: 32 rows x K=128 into registers + f2 on the fly ----
    short8 a[2][4];
    float  t[2][4];
    int    tg[2][4];
    #pragma unroll
    for (int rg = 0; rg < 2; ++rg) {
        const float* ap = feat + (size_t)(row0 + rg * 16 + l15) * D_N + kg * 8;
        float s = 0.f;
        #pragma unroll
        for (int kk = 0; kk < 4; ++kk) {
            float4 v0 = *reinterpret_cast<const float4*>(ap + kk * 32);
            float4 v1 = *reinterpret_cast<const float4*>(ap + kk * 32 + 4);
            s += v0.x*v0.x + v0.y*v0.y + v0.z*v0.z + v0.w*v0.w
               + v1.x*v1.x + v1.y*v1.y + v1.z*v1.z + v1.w*v1.w;
            a[rg][kk] = cvt8(v0, v1);
        }
        s += __shfl_xor(s, 16);
        s += __shfl_xor(s, 32);
        #pragma unroll
        for (int r = 0; r < 4; ++r) {
            t[rg][r]  = MARGIN - __shfl(s, kg * 4 + r);
            tg[rg][r] = (int)tgt[row0 + rg * 16 + kg * 4 + r];  // int64 input
        }
    }

    // ---- main loop: 8 col-blocks x {4 B-frag loads, 8 MFMA, epilogue} ----
    float hsum = 0.f;
    #pragma unroll 2
    for (int i = 0; i < 8; ++i) {
        const int nb = nb0 + i;
        const short8* bp =
            reinterpret_cast<const short8*>(bpre + (size_t)nb * 2048) + lane;
        short8 b0 = bp[0];
        short8 b1 = bp[64];
        short8 b2 = bp[128];
        short8 b3 = bp[192];
        f32x4 acc0 = (f32x4){0.f, 0.f, 0.f, 0.f};
        f32x4 acc1 = (f32x4){0.f, 0.f, 0.f, 0.f};
        acc0 = __builtin_amdgcn_mfma_f32_16x16x32_bf16(a[0][0], b0, acc0, 0, 0, 0);
        acc1 = __builtin_amdgcn_mfma_f32_16x16x32_bf16(a[1][0], b0, acc1, 0, 0, 0);
        acc0 = __builtin_amdgcn_mfma_f32_16x16x32_bf16(a[0][1], b1, acc0, 0, 0, 0);
        acc1 = __builtin_amdgcn_mfma_f32_16x16x32_bf16(a[1][1], b1, acc1, 0, 0, 0);
        acc0 = __builtin_amdgcn_mfma_f32_16x16x32_bf16(a[0][2], b2, acc0, 0, 0, 0);
        acc1 = __builtin_amdgcn_mfma_f32_16x16x32_bf16(a[1][2], b2, acc1, 0, 0, 0);
        acc0 = __builtin_amdgcn_mfma_f32_16x16x32_bf16(a[0][3], b3, acc0, 0, 0, 0);
        acc1 = __builtin_amdgcn_mfma_f32_16x16x32_bf16(a[1][3], b3, acc1, 0, 0, 0);

        // Epilogue. C/D layout (m89): col = lane&15, row = kg*4 + r.
        // u = 2*acc + (MARGIN - f2 - c2); hinge active iff u > 0 (~never).
        float u[2][4];
        float mx = -1.0f;
        #pragma unroll
        for (int r = 0; r < 4; ++r) {
            u[0][r] = __builtin_fmaf(2.0f, acc0[r], t[0][r] - c2v[i]);
            u[1][r] = __builtin_fmaf(2.0f, acc1[r], t[1][r] - c2v[i]);
            mx = fmaxf(mx, fmaxf(u[0][r], u[1][r]));
        }
        if (__any(mx > 0.0f)) {   // wave-uniform slow path (mask + accumulate)
            const int col = nb * 16 + l15;
            #pragma unroll
            for (int r = 0; r < 4; ++r) {
                hsum += (col != tg[0][r]) ? fmaxf(0.0f, u[0][r]) : 0.0f;
                hsum += (col != tg[1][r]) ? fmaxf(0.0f, u[1][r]) : 0.0f;
            }
        }
    }

    // ---- reduce: wave -> block -> plain store (no contended atomics) ----
    #pragma unroll
    for (int off = 32; off; off >>= 1) hsum += __shfl_down(hsum, off);
    __shared__ float ws[4];
    if (lane == 0) ws[wave] = hsum;
    __syncthreads();
    if (tid == 0)
        part[blockIdx.y * gridDim.x + blockIdx.x] = ws[0] + ws[1] + ws[2] + ws[3];
}

// ---- kernel 3: reduce 1024 partials -> out[0] ----
__global__ __launch_bounds__(256) void reduce_kernel(
    const float* __restrict__ part, float* __restrict__ out)
{
    const int tid = threadIdx.x;
    float s = part[tid] + part[tid + 256] + part[tid + 512] + part[tid + 768];
    #pragma unroll
    for (int off = 32; off; off >>= 1) s += __shfl_down(s, off);
    __shared__ float ws[4];
    if ((tid & 63) == 0) ws[tid >> 6] = s;
    __syncthreads();
    if (tid == 0) out[0] = (ws[0] + ws[1] + ws[2] + ws[3]) * (1.0f / 16384.0f);
}

extern "C" void kernel_launch(void* const* d_in, const int* in_sizes, int n_in,
                              void* d_out, int out_size, void* d_ws, size_t ws_size,
                              hipStream_t stream) {
    const float*     feat = (const float*)d_in[0];
    const long long* tgt  = (const long long*)d_in[1];   // int64 targets
    const float*     cls  = (const float*)d_in[2];
    float*           out  = (float*)d_out;

    short* bpre = (short*)d_ws;                                      // 256 KiB
    float* c2p  = (float*)((char*)d_ws + 64 * 2048 * sizeof(short)); // 4 KiB
    float* part = c2p + 1024;                                        // 4 KiB

    prep_kernel<<<64, 64, 0, stream>>>(cls, bpre, c2p);
    closs_kernel<<<dim3(8, 128), 256, 0, stream>>>(feat, tgt, bpre, c2p, part);
    reduce_kernel<<<1, 256, 0, stream>>>(part, out);
}

// Round 9
// 24.884 us; speedup vs baseline: 1.7677x; 1.1760x over previous
//
#include <hip/hip_runtime.h>
#include <stdint.h>

// Contrastive loss: B=16384, C=1000, D=128, fp32 in, scalar fp32 out.
// dist = f2 + c2 - 2*cross; loss = sum(relu(1-dist) over j!=target)/B.
//
// Round 9: r3's best body (16-row waves, 4 waves/SIMD, unroll-4 over 16
// col-blocks) + explicit bijective XCD swizzle giving each XCD a disjoint
// 1/8 of feat rows (feat enters each XCD L2 exactly once: 8.4 MB unique vs
// r3's ~34 MB 4x cross-XCD re-fetch) + r8's wave-uniform __any epilogue
// fast path. Lessons kept: no same-addr atomics (r2/r7: ~16ns each,
// serialized device-wide), B converted once by prep (r6), 3 plain nodes.
#define B_N 16384
#define C_N 1000
#define D_N 128
#define NB_TOT 64          // 1024 padded columns / 16
#define MARGIN 1.0f
#define NBLK 1024

typedef __attribute__((ext_vector_type(8))) short short8;  // 8 bf16
typedef __attribute__((ext_vector_type(4))) float f32x4;   // MFMA acc

__device__ __forceinline__ short f2bf(float f) {
    union { float f; uint32_t u; } v; v.f = f;
    uint32_t u = v.u;
    return (short)((u + 0x7FFFu + ((u >> 16) & 1u)) >> 16);
}

__device__ __forceinline__ short8 cvt8(const float4& v0, const float4& v1) {
    short8 s;
    s[0] = f2bf(v0.x); s[1] = f2bf(v0.y); s[2] = f2bf(v0.z); s[3] = f2bf(v0.w);
    s[4] = f2bf(v1.x); s[5] = f2bf(v1.y); s[6] = f2bf(v1.z); s[7] = f2bf(v1.w);
    return s;
}

// ---- kernel 1: cls -> bf16 fragment order + c2 (1e30 sentinel past C_N).
// Fragment (nb,kk): lane (l15,kg) holds cls[nb*16+l15][kk*32+kg*8 .. +8]
// at shorts nb*2048 + kk*512 + lane*8.
__global__ __launch_bounds__(64) void prep_kernel(
    const float* __restrict__ cls, short* __restrict__ bpre,
    float* __restrict__ c2p)
{
    const int nb   = blockIdx.x;       // 0..63
    const int lane = threadIdx.x;      // 0..63
    const int l15  = lane & 15;
    const int kg   = lane >> 4;
    const int col  = nb * 16 + l15;
    const bool valid = col < C_N;

    float sq = 0.f;
    #pragma unroll
    for (int kk = 0; kk < 4; ++kk) {
        float4 v0 = make_float4(0.f, 0.f, 0.f, 0.f);
        float4 v1 = make_float4(0.f, 0.f, 0.f, 0.f);
        if (valid) {
            const float* p = cls + (size_t)col * D_N + kk * 32 + kg * 8;
            v0 = *reinterpret_cast<const float4*>(p);
            v1 = *reinterpret_cast<const float4*>(p + 4);
        }
        sq += v0.x*v0.x + v0.y*v0.y + v0.z*v0.z + v0.w*v0.w
            + v1.x*v1.x + v1.y*v1.y + v1.z*v1.z + v1.w*v1.w;
        *reinterpret_cast<short8*>(bpre + (size_t)(nb * 2048 + kk * 512 + lane * 8))
            = cvt8(v0, v1);
    }
    sq += __shfl_xor(sq, 16);
    sq += __shfl_xor(sq, 32);
    if (lane < 16)
        c2p[nb * 16 + lane] = ((nb * 16 + lane) < C_N) ? sq : 1e30f;
}

// ---- kernel 2: r3 body + XCD row-ownership swizzle ----
// 1024 blocks. xcd = bid&7 owns row-tiles [xcd*32, xcd*32+32) x 4 col-slices
// (bijective: by = xcd*32 + idx/4, bx = idx&3, idx = bid>>3). Under bid%8
// round-robin dispatch, each XCD's L2 then sees a disjoint 1/8 of feat.
__global__ __launch_bounds__(256, 4) void closs_kernel(
    const float* __restrict__ feat, const long long* __restrict__ tgt,
    const short* __restrict__ bpre, const float* __restrict__ c2p,
    float* __restrict__ part)
{
    const int tid  = threadIdx.x;
    const int wave = tid >> 6;
    const int lane = tid & 63;
    const int l15  = lane & 15;
    const int kg   = lane >> 4;

    const int bid  = blockIdx.x;
    const int xcd  = bid & 7;
    const int idx  = bid >> 3;
    const int by   = (xcd << 5) | (idx >> 2);   // 0..255  row-tile (64 rows)
    const int bx   = idx & 3;                   // 0..3    col-slice (256 cols)
    const int row0 = by * 64 + wave * 16;       // wave's 16-row base
    const int nb0  = bx * 16;                   // 16 col-blocks per wave

    // ---- A fragments (16 rows x K=128) into registers + f2 on the fly ----
    short8 a[4];
    float sq = 0.f;
    const float* ap = feat + (size_t)(row0 + l15) * D_N + kg * 8;
    #pragma unroll
    for (int kk = 0; kk < 4; ++kk) {
        float4 v0 = *reinterpret_cast<const float4*>(ap + kk * 32);
        float4 v1 = *reinterpret_cast<const float4*>(ap + kk * 32 + 4);
        sq += v0.x*v0.x + v0.y*v0.y + v0.z*v0.z + v0.w*v0.w
            + v1.x*v1.x + v1.y*v1.y + v1.z*v1.z + v1.w*v1.w;
        a[kk] = cvt8(v0, v1);
    }
    sq += __shfl_xor(sq, 16);
    sq += __shfl_xor(sq, 32);
    float t[4]; int tg[4];
    #pragma unroll
    for (int r = 0; r < 4; ++r) {
        t[r]  = MARGIN - __shfl(sq, kg * 4 + r);
        tg[r] = (int)tgt[row0 + kg * 4 + r];        // int64 targets
    }

    // ---- main loop: 16 col-blocks x {4 B-frag loads, 4 MFMA, epilogue} ----
    float hsum = 0.f;
    #pragma unroll 4
    for (int i = 0; i < 16; ++i) {
        const int nb = nb0 + i;
        const short8* bp =
            reinterpret_cast<const short8*>(bpre + (size_t)nb * 2048) + lane;
        short8 b0 = bp[0];
        short8 b1 = bp[64];
        short8 b2 = bp[128];
        short8 b3 = bp[192];
        f32x4 acc = (f32x4){0.f, 0.f, 0.f, 0.f};
        acc = __builtin_amdgcn_mfma_f32_16x16x32_bf16(a[0], b0, acc, 0, 0, 0);
        acc = __builtin_amdgcn_mfma_f32_16x16x32_bf16(a[1], b1, acc, 0, 0, 0);
        acc = __builtin_amdgcn_mfma_f32_16x16x32_bf16(a[2], b2, acc, 0, 0, 0);
        acc = __builtin_amdgcn_mfma_f32_16x16x32_bf16(a[3], b3, acc, 0, 0, 0);

        // Epilogue. C/D layout (m89): col = lane&15, row = kg*4 + r.
        // u = 2*acc + (MARGIN - f2 - c2); hinge active iff u > 0 (~never).
        const int   col = nb * 16 + l15;
        const float c2v = c2p[col];     // 1e30 for padded cols -> u < 0
        float u[4];
        float mx;
        u[0] = __builtin_fmaf(2.0f, acc[0], t[0] - c2v);
        u[1] = __builtin_fmaf(2.0f, acc[1], t[1] - c2v);
        u[2] = __builtin_fmaf(2.0f, acc[2], t[2] - c2v);
        u[3] = __builtin_fmaf(2.0f, acc[3], t[3] - c2v);
        mx = fmaxf(fmaxf(u[0], u[1]), fmaxf(u[2], u[3]));
        if (__any(mx > 0.0f)) {   // wave-uniform slow path: mask + accumulate
            #pragma unroll
            for (int r = 0; r < 4; ++r)
                hsum += (col != tg[r]) ? fmaxf(0.0f, u[r]) : 0.0f;
        }
    }

    // ---- reduce: wave -> block -> plain store (no contended atomics) ----
    #pragma unroll
    for (int off = 32; off; off >>= 1) hsum += __shfl_down(hsum, off);
    __shared__ float ws[4];
    if (lane == 0) ws[wave] = hsum;
    __syncthreads();
    if (tid == 0)
        part[bid] = ws[0] + ws[1] + ws[2] + ws[3];
}

// ---- kernel 3: reduce 1024 partials -> out[0] ----
__global__ __launch_bounds__(256) void reduce_kernel(
    const float* __restrict__ part, float* __restrict__ out)
{
    const int tid = threadIdx.x;
    float s = part[tid] + part[tid + 256] + part[tid + 512] + part[tid + 768];
    #pragma unroll
    for (int off = 32; off; off >>= 1) s += __shfl_down(s, off);
    __shared__ float ws[4];
    if ((tid & 63) == 0) ws[tid >> 6] = s;
    __syncthreads();
    if (tid == 0) out[0] = (ws[0] + ws[1] + ws[2] + ws[3]) * (1.0f / 16384.0f);
}

extern "C" void kernel_launch(void* const* d_in, const int* in_sizes, int n_in,
                              void* d_out, int out_size, void* d_ws, size_t ws_size,
                              hipStream_t stream) {
    const float*     feat = (const float*)d_in[0];
    const long long* tgt  = (const long long*)d_in[1];   // int64 targets
    const float*     cls  = (const float*)d_in[2];
    float*           out  = (float*)d_out;

    short* bpre = (short*)d_ws;                                      // 256 KiB
    float* c2p  = (float*)((char*)d_ws + 64 * 2048 * sizeof(short)); // 4 KiB
    float* part = c2p + 1024;                                        // 4 KiB

    prep_kernel<<<64, 64, 0, stream>>>(cls, bpre, c2p);
    closs_kernel<<<NBLK, 256, 0, stream>>>(feat, tgt, bpre, c2p, part);
    reduce_kernel<<<1, 256, 0, stream>>>(part, out);
}